// Round 5
// baseline (264.099 us; speedup 1.0000x reference)
//
#include <hip/hip_runtime.h>
#include <hip/hip_bf16.h>

#pragma clang fp contract(off)

typedef unsigned long long ull;

#define B_IMG   16
#define N_ELEM  1000000
#define PRE_NMS 2000
#define POST_NMS 1000
#define KEY_BITS 13
#define NBINS   (1 << KEY_BITS)       // 8192
#define KEY_SHIFT (32 - KEY_BITS)     // 19
#define CAP     4096
#define SORT_N  4096
#define KPAD    2048

// workspace layout (bytes)
#define OFF_HIST   0u                        // 16*8192*4   = 512KB
#define OFF_CNT    (512u*1024u)              // 16*4
#define OFF_KEYLO  (512u*1024u + 256u)       // 16*4
#define OFF_CAND   (1024u*1024u)             // 16*4096*8   = 512KB
#define OFF_BOXES  (1536u*1024u)             // 16*2048*8   = 256KB
#define OFF_VALID  (1792u*1024u)             // 16*32*8     = 4KB
#define OFF_DSPAN  (1800u*1024u)             // 16*2048*8   = 256KB
#define OFF_MAT    (2304u*1024u)             // 16*2048*32*8 = 8MB

__device__ __forceinline__ unsigned fkey(float f) {
  unsigned u = __float_as_uint(f);
  return (u & 0x80000000u) ? ~u : (u | 0x80000000u);
}

__device__ __forceinline__ ull shfl64(ull x, int src) {
  int lo = __shfl((int)(unsigned)(x & 0xffffffffull), src);
  int hi = __shfl((int)(unsigned)(x >> 32), src);
  return ((ull)(unsigned)hi << 32) | (ull)(unsigned)lo;
}

// ---------------- 1. per-image histogram of 13-bit keys ----------------
__global__ __launch_bounds__(512) void k_hist(const float* __restrict__ obj,
                                              unsigned* __restrict__ hist) {
  __shared__ unsigned h[NBINS];
  const int img = blockIdx.x >> 4;   // 16 blocks per image
  const int chunk = blockIdx.x & 15;
  for (int i = threadIdx.x; i < NBINS; i += 512) h[i] = 0u;
  __syncthreads();
  const int nv = N_ELEM / 4 / 16;    // 15625 float4 per chunk
  const float4* src = (const float4*)obj + (size_t)img * (N_ELEM / 4) + (size_t)chunk * nv;
  for (int v = threadIdx.x; v < nv; v += 512) {
    float4 x = src[v];
    atomicAdd(&h[fkey(x.x) >> KEY_SHIFT], 1u);
    atomicAdd(&h[fkey(x.y) >> KEY_SHIFT], 1u);
    atomicAdd(&h[fkey(x.z) >> KEY_SHIFT], 1u);
    atomicAdd(&h[fkey(x.w) >> KEY_SHIFT], 1u);
  }
  __syncthreads();
  unsigned* gh = hist + (size_t)img * NBINS;
  for (int i = threadIdx.x; i < NBINS; i += 512) {
    unsigned c = h[i];
    if (c) atomicAdd(&gh[i], c);
  }
}

// ---------------- 2. find per-image key threshold (2000th element's bin) ----------------
__global__ __launch_bounds__(256) void k_thresh(const unsigned* __restrict__ hist,
                                                unsigned* __restrict__ keylo) {
  const int img = blockIdx.x;
  const unsigned* gh = hist + (size_t)img * NBINS;
  __shared__ unsigned part[256];
  const int t = threadIdx.x;
  unsigned s = 0;
  const int hi = NBINS - 32 * t;     // exclusive top of this thread's region
  for (int b = hi - 32; b < hi; ++b) s += gh[b];
  part[t] = s;
  __syncthreads();
  if (t == 0) {
    unsigned acc = 0, excl = 0;
    int tstar = 255;
    for (int q = 0; q < 256; ++q) {
      unsigned na = acc + part[q];
      if (na >= PRE_NMS) { tstar = q; excl = acc; break; }
      acc = na;
    }
    const int bh = NBINS - 32 * tstar;
    unsigned a2 = excl, kl = 0;
    for (int b = bh - 1; b >= bh - 32; --b) {
      a2 += gh[b];
      if (a2 >= PRE_NMS) { kl = ((unsigned)b) << KEY_SHIFT; break; }
    }
    keylo[img] = kl;
  }
}

// ---------------- 3. compact candidates >= threshold (LDS-staged) ----------------
#define NCHUNKS 50
#define LCAP    1024

__global__ __launch_bounds__(512) void k_compact(const float* __restrict__ obj,
                                                 const unsigned* __restrict__ keylo,
                                                 unsigned* __restrict__ cnt,
                                                 ull* __restrict__ cand) {
  __shared__ ull lbuf[LCAP];
  __shared__ unsigned lcnt, sbase, slen;
  const int img = blockIdx.x / NCHUNKS;
  const int chunk = blockIdx.x % NCHUNKS;
  if (threadIdx.x == 0) lcnt = 0u;
  __syncthreads();
  const unsigned kl = keylo[img];
  const int nv = N_ELEM / 4 / NCHUNKS;   // 5000 float4 per chunk
  const float4* src = (const float4*)obj + (size_t)img * (N_ELEM / 4) + (size_t)chunk * nv;
  const unsigned base_idx = (unsigned)chunk * (N_ELEM / NCHUNKS);
  for (int v = threadIdx.x; v < nv; v += 512) {
    float4 x = src[v];
    unsigned k0 = fkey(x.x), k1 = fkey(x.y), k2 = fkey(x.z), k3 = fkey(x.w);
    unsigned bi = base_idx + 4u * (unsigned)v;
    if (k0 >= kl) { unsigned p = atomicAdd(&lcnt, 1u); if (p < LCAP) lbuf[p] = ((ull)k0 << 32) | (unsigned)(~bi); }
    if (k1 >= kl) { unsigned p = atomicAdd(&lcnt, 1u); if (p < LCAP) lbuf[p] = ((ull)k1 << 32) | (unsigned)(~(bi + 1u)); }
    if (k2 >= kl) { unsigned p = atomicAdd(&lcnt, 1u); if (p < LCAP) lbuf[p] = ((ull)k2 << 32) | (unsigned)(~(bi + 2u)); }
    if (k3 >= kl) { unsigned p = atomicAdd(&lcnt, 1u); if (p < LCAP) lbuf[p] = ((ull)k3 << 32) | (unsigned)(~(bi + 3u)); }
  }
  __syncthreads();
  if (threadIdx.x == 0) {
    unsigned n = lcnt; if (n > LCAP) n = LCAP;
    slen = n;
    sbase = n ? atomicAdd(&cnt[img], n) : 0u;
  }
  __syncthreads();
  ull* cimg = cand + (size_t)img * CAP;
  const unsigned b0 = sbase, n0 = slen;
  for (unsigned i = threadIdx.x; i < n0; i += 512) {
    unsigned p = b0 + i;
    if (p < CAP) cimg[p] = lbuf[i];
  }
}

// ---------------- 4. per-image bitonic sort + decode/clip/width-mask ----------------
__global__ __launch_bounds__(1024) void k_sortdecode(const ull* __restrict__ cand,
                                                     const unsigned* __restrict__ cnt,
                                                     const float2* __restrict__ delta,
                                                     const float2* __restrict__ anchor,
                                                     float2* __restrict__ boxes,
                                                     ull* __restrict__ validm) {
  __shared__ ull sk[SORT_N];
  const int img = blockIdx.x;
  unsigned M = cnt[img]; if (M > CAP) M = CAP;
  const ull* cimg = cand + (size_t)img * CAP;
  for (int i = threadIdx.x; i < SORT_N; i += 1024) sk[i] = (i < (int)M) ? cimg[i] : 0ull;
  __syncthreads();
  for (int k = 2; k <= SORT_N; k <<= 1) {
    for (int j = k >> 1; j > 0; j >>= 1) {
      for (int p = threadIdx.x; p < SORT_N / 2; p += 1024) {
        int i = ((p & ~(j - 1)) << 1) | (p & (j - 1));
        int ixj = i | j;
        ull a = sk[i], b = sk[ixj];
        bool asc = (i & k) != 0;
        bool sw = asc ? (a > b) : (a < b);   // overall descending
        if (sw) { sk[i] = b; sk[ixj] = a; }
      }
      __syncthreads();
    }
  }
  // decode top PRE_NMS, write padded boxes + validity ballot
  for (int i = threadIdx.x; i < KPAD; i += 1024) {
    float bx0 = 0.f, bx1 = 0.f;
    bool valid = false;
    if (i < PRE_NMS) {
      ull e = sk[i];
      unsigned idx = ~((unsigned)e);
      float2 d = delta[(size_t)img * N_ELEM + idx];
      float2 a = anchor[(size_t)img * N_ELEM + idx];
      float aw = a.y - a.x;
      float ac = a.x + 0.5f * aw;
      float dx = d.x;
      float dw = fminf(d.y, 4.135f);
      float pc = dx * aw + ac;
      float pw = expf(dw) * aw;
      float x0 = pc - 0.5f * pw;
      float x1 = pc + 0.5f * pw;
      x0 = fminf(fmaxf(x0, 0.f), 360.f);
      x1 = fminf(fmaxf(x1, 0.f), 360.f);
      bx0 = x0; bx1 = x1;
      valid = (x1 - x0) >= 10.0f;
    }
    boxes[(size_t)img * KPAD + i] = make_float2(bx0, bx1);
    ull bm = __ballot(valid);
    if ((threadIdx.x & 63) == 0) validm[img * 32 + (i >> 6)] = bm;
  }
}

// ---------------- 5. suppression bit-matrix, wave-per-64x64-tile ----------------
__global__ __launch_bounds__(256) void k_matrix(const float2* __restrict__ boxes,
                                                ull* __restrict__ mat,
                                                ull* __restrict__ dspan) {
  const int wid = blockIdx.x * 4 + (threadIdx.x >> 6);   // global wave/tile id
  const int lane = threadIdx.x & 63;
  const int img = wid >> 10;          // 32*32 tiles per image
  const int RI = (wid >> 5) & 31;
  const int CJ = wid & 31;
  ull* mimg = mat + (size_t)img * KPAD * 32;
  ull myword = 0ull;
  if (CJ >= RI) {
    const float2* bimg = boxes + (size_t)img * KPAD;
    float2 rb = bimg[RI * 64 + lane];   // row boxes (this lane holds row `lane`)
    float2 cb = bimg[CJ * 64 + lane];   // col box for this lane
    float acol = cb.y - cb.x;
    const bool diag = (RI == CJ);
#pragma unroll 8
    for (int i = 0; i < 64; ++i) {
      float b0x = __uint_as_float((unsigned)__builtin_amdgcn_readlane((int)__float_as_uint(rb.x), i));
      float b0y = __uint_as_float((unsigned)__builtin_amdgcn_readlane((int)__float_as_uint(rb.y), i));
      float a0 = b0y - b0x;
      float lo = fmaxf(b0x, cb.x);
      float hi = fminf(b0y, cb.y);
      float inter = fmaxf(hi - lo, 0.f);
      float den = fmaxf((a0 + acol) - inter, 1e-8f);
      bool sup = (inter / den) > 0.7f;
      if (diag) sup = sup && (lane > i);
      ull bm = __ballot(sup);
      if (lane == i) myword = bm;
    }
    if (diag) dspan[(size_t)img * KPAD + RI * 64 + lane] = myword;
  }
  mimg[(size_t)(RI * 64 + lane) * 32 + CJ] = myword;
}

// ---------------- 6. serial greedy scan + compact output ----------------
// Serial chain per row: dead = bit(i&63) of cur; cur |= D[i] if alive.
// mat rows (r) and dspan words (d) prefetched 2 chunks ahead into static
// register arrays. Three levers to make the pipeline REAL this time:
//  (1) __launch_bounds__(64,1): 16 single-wave blocks; allow ~512 VGPRs so
//      the ~200-VGPR triple buffer materializes (R4 showed 72 VGPR = collapsed).
//  (2) d loaded as ulonglong2 (8x16B): 24 loads/chunk -> 48 in flight at each
//      use, so counted vmcnt(48) is encodable (6-bit max 63; R3 needed 64).
//  (3) asm memory clobber after each LOADF: loads cannot sink past it, uses
//      are after it -> values must live in registers across the boundary.
#define CH 16

__global__ __launch_bounds__(64, 1) void k_scan(const ull* __restrict__ mat,
                                                const ull* __restrict__ dspan,
                                                const ull* __restrict__ validm,
                                                const float2* __restrict__ boxes,
                                                float2* __restrict__ out) {
  const int img = blockIdx.x;
  const int lane = threadIdx.x;
  const int w = lane & 31;
  ull removed = ~validm[img * 32 + w];
  const ull* Mr = mat + (size_t)img * KPAD * 32 + w;
  const ull* D = dspan + (size_t)img * KPAD;
  ull cur = 0ull;

  ull rA[CH], rB[CH], rC[CH];
  ull dA[CH], dB[CH], dC[CH];

#define LOADF(r, d, c) do {                                        \
    const ull* p_ = Mr + (size_t)(c) * CH * 32;                    \
    const ulonglong2* q_ = (const ulonglong2*)(D + (size_t)(c) * CH); \
    _Pragma("unroll")                                              \
    for (int u = 0; u < CH; ++u) r[u] = p_[(size_t)u * 32];        \
    _Pragma("unroll")                                              \
    for (int u = 0; u < CH / 2; ++u) {                             \
      ulonglong2 t2_ = q_[u];                                      \
      d[2 * u] = t2_.x; d[2 * u + 1] = t2_.y;                      \
    }                                                              \
    asm volatile("" ::: "memory");                                 \
  } while (0)

#define PROCF(r, d, c) do {                                        \
    if (((c) & 3) == 0) cur = shfl64(removed, (c) >> 2);           \
    _Pragma("unroll")                                              \
    for (int u = 0; u < CH; ++u) {                                 \
      int t_ = ((c) & 3) * CH + u;                                 \
      ull dead_ = (cur >> t_) & 1ull;                              \
      cur |= dead_ ? 0ull : d[u];                                  \
      removed |= dead_ ? 0ull : r[u];                              \
    }                                                              \
  } while (0)

  LOADF(rA, dA, 0);
  LOADF(rB, dB, 1);
  for (int g = 0; g <= 120; g += 3) {
    LOADF(rC, dC, g + 2); PROCF(rA, dA, g);
    LOADF(rA, dA, g + 3); PROCF(rB, dB, g + 1);
    LOADF(rB, dB, g + 4); PROCF(rC, dC, g + 2);
  }
  PROCF(rA, dA, 123);
  PROCF(rB, dB, 124);

#undef LOADF
#undef PROCF

  // keep mask = ~removed (bits i>=2000 are removed via validity)
  ull keep = ~removed;
  int cw = (lane < 32) ? __popcll(keep) : 0;
  int v = cw;
#pragma unroll
  for (int off = 1; off < 64; off <<= 1) {
    int n = __shfl_up(v, off);
    if (lane >= off) v += n;
  }
  int excl = v - cw;
  int total = __shfl(v, 63);
  if (lane < 32) {
    int r = excl;
    ull kk = keep;
    while (kk) {
      int t = __ffsll(kk) - 1;
      kk &= kk - 1;
      if (r < POST_NMS) {
        out[(size_t)img * POST_NMS + r] = boxes[(size_t)img * KPAD + (w * 64 + t)];
      }
      ++r;
    }
  }
  for (int r = total + lane; r < POST_NMS; r += 64) {
    out[(size_t)img * POST_NMS + r] = make_float2(0.f, 0.f);
  }
}

extern "C" void kernel_launch(void* const* d_in, const int* in_sizes, int n_in,
                              void* d_out, int out_size, void* d_ws, size_t ws_size,
                              hipStream_t stream) {
  const float* obj = (const float*)d_in[0];
  const float2* delta = (const float2*)d_in[1];
  const float2* anchor = (const float2*)d_in[2];
  float2* out = (float2*)d_out;
  char* ws = (char*)d_ws;

  unsigned* hist = (unsigned*)(ws + OFF_HIST);
  unsigned* cnt = (unsigned*)(ws + OFF_CNT);
  unsigned* keylo = (unsigned*)(ws + OFF_KEYLO);
  ull* cand = (ull*)(ws + OFF_CAND);
  float2* boxes = (float2*)(ws + OFF_BOXES);
  ull* validm = (ull*)(ws + OFF_VALID);
  ull* dspan = (ull*)(ws + OFF_DSPAN);
  ull* mat = (ull*)(ws + OFF_MAT);

  // zero hist + cnt (keylo overwritten)
  hipMemsetAsync(ws, 0, OFF_KEYLO + 4096, stream);

  k_hist<<<256, 512, 0, stream>>>(obj, hist);
  k_thresh<<<16, 256, 0, stream>>>(hist, keylo);
  k_compact<<<16 * NCHUNKS, 512, 0, stream>>>(obj, keylo, cnt, cand);
  k_sortdecode<<<16, 1024, 0, stream>>>(cand, cnt, delta, anchor, boxes, validm);
  k_matrix<<<4096, 256, 0, stream>>>(boxes, mat, dspan);
  k_scan<<<16, 64, 0, stream>>>(mat, dspan, validm, boxes, out);
}

// Round 6
// 244.914 us; speedup vs baseline: 1.0783x; 1.0783x over previous
//
#include <hip/hip_runtime.h>
#include <hip/hip_bf16.h>

#pragma clang fp contract(off)

typedef unsigned long long ull;

#define B_IMG   16
#define N_ELEM  1000000
#define PRE_NMS 2000
#define POST_NMS 1000
#define KEY_BITS 13
#define NBINS   (1 << KEY_BITS)       // 8192
#define KEY_SHIFT (32 - KEY_BITS)     // 19
#define CAP     4096
#define SORT_N  4096
#define KPAD    2048

// workspace layout (bytes)
#define OFF_HIST   0u                        // 16*8192*4   = 512KB
#define OFF_CNT    (512u*1024u)              // 16*4
#define OFF_KEYLO  (512u*1024u + 256u)       // 16*4
#define OFF_CAND   (1024u*1024u)             // 16*4096*8   = 512KB
#define OFF_BOXES  (1536u*1024u)             // 16*2048*8   = 256KB
#define OFF_VALID  (1792u*1024u)             // 16*32*8     = 4KB
#define OFF_DSPAN  (1800u*1024u)             // 16*2048*8   = 256KB
#define OFF_MAT    (2304u*1024u)             // 16*2048*32*8 = 8MB

__device__ __forceinline__ unsigned fkey(float f) {
  unsigned u = __float_as_uint(f);
  return (u & 0x80000000u) ? ~u : (u | 0x80000000u);
}

__device__ __forceinline__ ull readlane64(ull x, int l) {
  unsigned lo = (unsigned)__builtin_amdgcn_readlane((int)(unsigned)(x & 0xffffffffull), l);
  unsigned hi = (unsigned)__builtin_amdgcn_readlane((int)(unsigned)(x >> 32), l);
  return ((ull)hi << 32) | (ull)lo;
}

// ---------------- 1. per-image histogram of 13-bit keys ----------------
__global__ __launch_bounds__(512) void k_hist(const float* __restrict__ obj,
                                              unsigned* __restrict__ hist) {
  __shared__ unsigned h[NBINS];
  const int img = blockIdx.x >> 4;   // 16 blocks per image
  const int chunk = blockIdx.x & 15;
  for (int i = threadIdx.x; i < NBINS; i += 512) h[i] = 0u;
  __syncthreads();
  const int nv = N_ELEM / 4 / 16;    // 15625 float4 per chunk
  const float4* src = (const float4*)obj + (size_t)img * (N_ELEM / 4) + (size_t)chunk * nv;
  for (int v = threadIdx.x; v < nv; v += 512) {
    float4 x = src[v];
    atomicAdd(&h[fkey(x.x) >> KEY_SHIFT], 1u);
    atomicAdd(&h[fkey(x.y) >> KEY_SHIFT], 1u);
    atomicAdd(&h[fkey(x.z) >> KEY_SHIFT], 1u);
    atomicAdd(&h[fkey(x.w) >> KEY_SHIFT], 1u);
  }
  __syncthreads();
  unsigned* gh = hist + (size_t)img * NBINS;
  for (int i = threadIdx.x; i < NBINS; i += 512) {
    unsigned c = h[i];
    if (c) atomicAdd(&gh[i], c);
  }
}

// ---------------- 2. find per-image key threshold (2000th element's bin) ----------------
__global__ __launch_bounds__(256) void k_thresh(const unsigned* __restrict__ hist,
                                                unsigned* __restrict__ keylo) {
  const int img = blockIdx.x;
  const unsigned* gh = hist + (size_t)img * NBINS;
  __shared__ unsigned part[256];
  const int t = threadIdx.x;
  unsigned s = 0;
  const int hi = NBINS - 32 * t;     // exclusive top of this thread's region
  for (int b = hi - 32; b < hi; ++b) s += gh[b];
  part[t] = s;
  __syncthreads();
  if (t == 0) {
    unsigned acc = 0, excl = 0;
    int tstar = 255;
    for (int q = 0; q < 256; ++q) {
      unsigned na = acc + part[q];
      if (na >= PRE_NMS) { tstar = q; excl = acc; break; }
      acc = na;
    }
    const int bh = NBINS - 32 * tstar;
    unsigned a2 = excl, kl = 0;
    for (int b = bh - 1; b >= bh - 32; --b) {
      a2 += gh[b];
      if (a2 >= PRE_NMS) { kl = ((unsigned)b) << KEY_SHIFT; break; }
    }
    keylo[img] = kl;
  }
}

// ---------------- 3. compact candidates >= threshold (LDS-staged) ----------------
#define NCHUNKS 50
#define LCAP    1024

__global__ __launch_bounds__(512) void k_compact(const float* __restrict__ obj,
                                                 const unsigned* __restrict__ keylo,
                                                 unsigned* __restrict__ cnt,
                                                 ull* __restrict__ cand) {
  __shared__ ull lbuf[LCAP];
  __shared__ unsigned lcnt, sbase, slen;
  const int img = blockIdx.x / NCHUNKS;
  const int chunk = blockIdx.x % NCHUNKS;
  if (threadIdx.x == 0) lcnt = 0u;
  __syncthreads();
  const unsigned kl = keylo[img];
  const int nv = N_ELEM / 4 / NCHUNKS;   // 5000 float4 per chunk
  const float4* src = (const float4*)obj + (size_t)img * (N_ELEM / 4) + (size_t)chunk * nv;
  const unsigned base_idx = (unsigned)chunk * (N_ELEM / NCHUNKS);
  for (int v = threadIdx.x; v < nv; v += 512) {
    float4 x = src[v];
    unsigned k0 = fkey(x.x), k1 = fkey(x.y), k2 = fkey(x.z), k3 = fkey(x.w);
    unsigned bi = base_idx + 4u * (unsigned)v;
    if (k0 >= kl) { unsigned p = atomicAdd(&lcnt, 1u); if (p < LCAP) lbuf[p] = ((ull)k0 << 32) | (unsigned)(~bi); }
    if (k1 >= kl) { unsigned p = atomicAdd(&lcnt, 1u); if (p < LCAP) lbuf[p] = ((ull)k1 << 32) | (unsigned)(~(bi + 1u)); }
    if (k2 >= kl) { unsigned p = atomicAdd(&lcnt, 1u); if (p < LCAP) lbuf[p] = ((ull)k2 << 32) | (unsigned)(~(bi + 2u)); }
    if (k3 >= kl) { unsigned p = atomicAdd(&lcnt, 1u); if (p < LCAP) lbuf[p] = ((ull)k3 << 32) | (unsigned)(~(bi + 3u)); }
  }
  __syncthreads();
  if (threadIdx.x == 0) {
    unsigned n = lcnt; if (n > LCAP) n = LCAP;
    slen = n;
    sbase = n ? atomicAdd(&cnt[img], n) : 0u;
  }
  __syncthreads();
  ull* cimg = cand + (size_t)img * CAP;
  const unsigned b0 = sbase, n0 = slen;
  for (unsigned i = threadIdx.x; i < n0; i += 512) {
    unsigned p = b0 + i;
    if (p < CAP) cimg[p] = lbuf[i];
  }
}

// ---------------- 4. per-image bitonic sort + decode/clip/width-mask ----------------
__global__ __launch_bounds__(1024) void k_sortdecode(const ull* __restrict__ cand,
                                                     const unsigned* __restrict__ cnt,
                                                     const float2* __restrict__ delta,
                                                     const float2* __restrict__ anchor,
                                                     float2* __restrict__ boxes,
                                                     ull* __restrict__ validm) {
  __shared__ ull sk[SORT_N];
  const int img = blockIdx.x;
  unsigned M = cnt[img]; if (M > CAP) M = CAP;
  const ull* cimg = cand + (size_t)img * CAP;
  for (int i = threadIdx.x; i < SORT_N; i += 1024) sk[i] = (i < (int)M) ? cimg[i] : 0ull;
  __syncthreads();
  for (int k = 2; k <= SORT_N; k <<= 1) {
    for (int j = k >> 1; j > 0; j >>= 1) {
      for (int p = threadIdx.x; p < SORT_N / 2; p += 1024) {
        int i = ((p & ~(j - 1)) << 1) | (p & (j - 1));
        int ixj = i | j;
        ull a = sk[i], b = sk[ixj];
        bool asc = (i & k) != 0;
        bool sw = asc ? (a > b) : (a < b);   // overall descending
        if (sw) { sk[i] = b; sk[ixj] = a; }
      }
      __syncthreads();
    }
  }
  // decode top PRE_NMS, write padded boxes + validity ballot
  for (int i = threadIdx.x; i < KPAD; i += 1024) {
    float bx0 = 0.f, bx1 = 0.f;
    bool valid = false;
    if (i < PRE_NMS) {
      ull e = sk[i];
      unsigned idx = ~((unsigned)e);
      float2 d = delta[(size_t)img * N_ELEM + idx];
      float2 a = anchor[(size_t)img * N_ELEM + idx];
      float aw = a.y - a.x;
      float ac = a.x + 0.5f * aw;
      float dx = d.x;
      float dw = fminf(d.y, 4.135f);
      float pc = dx * aw + ac;
      float pw = expf(dw) * aw;
      float x0 = pc - 0.5f * pw;
      float x1 = pc + 0.5f * pw;
      x0 = fminf(fmaxf(x0, 0.f), 360.f);
      x1 = fminf(fmaxf(x1, 0.f), 360.f);
      bx0 = x0; bx1 = x1;
      valid = (x1 - x0) >= 10.0f;
    }
    boxes[(size_t)img * KPAD + i] = make_float2(bx0, bx1);
    ull bm = __ballot(valid);
    if ((threadIdx.x & 63) == 0) validm[img * 32 + (i >> 6)] = bm;
  }
}

// ---------------- 5. suppression bit-matrix, wave-per-64x64-tile ----------------
__global__ __launch_bounds__(256) void k_matrix(const float2* __restrict__ boxes,
                                                ull* __restrict__ mat,
                                                ull* __restrict__ dspan) {
  const int wid = blockIdx.x * 4 + (threadIdx.x >> 6);   // global wave/tile id
  const int lane = threadIdx.x & 63;
  const int img = wid >> 10;          // 32*32 tiles per image
  const int RI = (wid >> 5) & 31;
  const int CJ = wid & 31;
  ull* mimg = mat + (size_t)img * KPAD * 32;
  ull myword = 0ull;
  if (CJ >= RI) {
    const float2* bimg = boxes + (size_t)img * KPAD;
    float2 rb = bimg[RI * 64 + lane];   // row boxes (this lane holds row `lane`)
    float2 cb = bimg[CJ * 64 + lane];   // col box for this lane
    float acol = cb.y - cb.x;
    const bool diag = (RI == CJ);
#pragma unroll 8
    for (int i = 0; i < 64; ++i) {
      float b0x = __uint_as_float((unsigned)__builtin_amdgcn_readlane((int)__float_as_uint(rb.x), i));
      float b0y = __uint_as_float((unsigned)__builtin_amdgcn_readlane((int)__float_as_uint(rb.y), i));
      float a0 = b0y - b0x;
      float lo = fmaxf(b0x, cb.x);
      float hi = fminf(b0y, cb.y);
      float inter = fmaxf(hi - lo, 0.f);
      float den = fmaxf((a0 + acol) - inter, 1e-8f);
      bool sup = (inter / den) > 0.7f;
      if (diag) sup = sup && (lane > i);
      ull bm = __ballot(sup);
      if (lane == i) myword = bm;
    }
    if (diag) dspan[(size_t)img * KPAD + RI * 64 + lane] = myword;
  }
  mimg[(size_t)(RI * 64 + lane) * 32 + CJ] = myword;
}

// ---------------- 6. tile-structured greedy scan + compact output ----------------
// Per tile t (64 rows):
//   scan : wave-uniform SALU greedy over the 64 diag words (dspan), which lane j
//          holds in a register (prefetched one tile ahead); readlane broadcasts
//          are off the serial chain. alive is a uniform 64-bit mask.
//   apply: 64 straight-line independent loads mat[64t+j][w], OR'd into `removed`
//          under uniform alive masks. No serial chain -> loads batch-issue.
//          Predicated on w>=t (lower-triangle words are zero by construction).
// No cross-phase register buffers for the compiler to collapse.
__global__ __launch_bounds__(64, 1) void k_scan(const ull* __restrict__ mat,
                                                const ull* __restrict__ dspan,
                                                const ull* __restrict__ validm,
                                                const float2* __restrict__ boxes,
                                                float2* __restrict__ out) {
  const int img = blockIdx.x;
  const int lane = threadIdx.x;
  const int w = lane & 31;
  const ull* Mimg = mat + (size_t)img * KPAD * 32;
  const ull* D = dspan + (size_t)img * KPAD;
  ull rm = ~validm[img * 32 + w];   // lanes 32..63 mirror lanes 0..31

  ull dsp_cur = D[lane];            // lane j holds dspan[64*0 + j]
  for (int t = 0; t < 32; ++t) {
    ull dsp_nxt = (t < 31) ? D[64 * (t + 1) + lane] : 0ull;

    // ---- serial scan of tile t (wave-uniform) ----
    ull alive = ~readlane64(rm, t);    // rm word t lives in lane t
#pragma unroll
    for (int j = 0; j < 64; ++j) {
      ull dj = readlane64(dsp_cur, j);             // off-chain broadcast
      ull mj = 0ull - ((alive >> j) & 1ull);       // uniform mask
      alive &= ~(dj & mj);
    }

    // ---- apply tile t's suppression to all future words ----
    if (w >= t) {
      const ull* rowp = Mimg + (size_t)(64 * t) * 32 + w;
#pragma unroll
      for (int j = 0; j < 64; ++j) {
        ull mj = 0ull - ((alive >> j) & 1ull);
        rm |= mj & rowp[(size_t)j * 32];
      }
    }
    dsp_cur = dsp_nxt;
  }

  // keep mask = ~rm (rows >= 2000 were marked invalid -> removed)
  ull keep = ~rm;
  int cw = (lane < 32) ? __popcll(keep) : 0;
  int v = cw;
#pragma unroll
  for (int off = 1; off < 64; off <<= 1) {
    int n = __shfl_up(v, off);
    if (lane >= off) v += n;
  }
  int excl = v - cw;
  int total = __shfl(v, 63);
  if (lane < 32) {
    int r = excl;
    ull kk = keep;
    while (kk) {
      int t = __ffsll(kk) - 1;
      kk &= kk - 1;
      if (r < POST_NMS) {
        out[(size_t)img * POST_NMS + r] = boxes[(size_t)img * KPAD + (w * 64 + t)];
      }
      ++r;
    }
  }
  for (int r = total + lane; r < POST_NMS; r += 64) {
    out[(size_t)img * POST_NMS + r] = make_float2(0.f, 0.f);
  }
}

extern "C" void kernel_launch(void* const* d_in, const int* in_sizes, int n_in,
                              void* d_out, int out_size, void* d_ws, size_t ws_size,
                              hipStream_t stream) {
  const float* obj = (const float*)d_in[0];
  const float2* delta = (const float2*)d_in[1];
  const float2* anchor = (const float2*)d_in[2];
  float2* out = (float2*)d_out;
  char* ws = (char*)d_ws;

  unsigned* hist = (unsigned*)(ws + OFF_HIST);
  unsigned* cnt = (unsigned*)(ws + OFF_CNT);
  unsigned* keylo = (unsigned*)(ws + OFF_KEYLO);
  ull* cand = (ull*)(ws + OFF_CAND);
  float2* boxes = (float2*)(ws + OFF_BOXES);
  ull* validm = (ull*)(ws + OFF_VALID);
  ull* dspan = (ull*)(ws + OFF_DSPAN);
  ull* mat = (ull*)(ws + OFF_MAT);

  // zero hist + cnt (keylo overwritten)
  hipMemsetAsync(ws, 0, OFF_KEYLO + 4096, stream);

  k_hist<<<256, 512, 0, stream>>>(obj, hist);
  k_thresh<<<16, 256, 0, stream>>>(hist, keylo);
  k_compact<<<16 * NCHUNKS, 512, 0, stream>>>(obj, keylo, cnt, cand);
  k_sortdecode<<<16, 1024, 0, stream>>>(cand, cnt, delta, anchor, boxes, validm);
  k_matrix<<<4096, 256, 0, stream>>>(boxes, mat, dspan);
  k_scan<<<16, 64, 0, stream>>>(mat, dspan, validm, boxes, out);
}

// Round 7
// 217.038 us; speedup vs baseline: 1.2168x; 1.1284x over previous
//
#include <hip/hip_runtime.h>
#include <hip/hip_bf16.h>

#pragma clang fp contract(off)

typedef unsigned long long ull;

#define B_IMG   16
#define N_ELEM  1000000
#define PRE_NMS 2000
#define POST_NMS 1000
#define KEY_BITS 13
#define NBINS   (1 << KEY_BITS)       // 8192
#define KEY_SHIFT (32 - KEY_BITS)     // 19
#define CAP     4096
#define SORT_N  4096
#define KPAD    2048

// workspace layout (bytes)
#define OFF_HIST   0u                        // 16*8192*4   = 512KB
#define OFF_CNT    (512u*1024u)              // 16*4
#define OFF_KEYLO  (512u*1024u + 256u)       // 16*4
#define OFF_CAND   (1024u*1024u)             // 16*4096*8   = 512KB
#define OFF_BOXES  (1536u*1024u)             // 16*2048*8   = 256KB
#define OFF_VALID  (1792u*1024u)             // 16*32*8     = 4KB
#define OFF_DSPAN  (1800u*1024u)             // 16*2048*8   = 256KB
#define OFF_MAT    (2304u*1024u)             // 16*2048*32*8 = 8MB

__device__ __forceinline__ unsigned fkey(float f) {
  unsigned u = __float_as_uint(f);
  return (u & 0x80000000u) ? ~u : (u | 0x80000000u);
}

__device__ __forceinline__ ull readlane64(ull x, int l) {
  unsigned lo = (unsigned)__builtin_amdgcn_readlane((int)(unsigned)(x & 0xffffffffull), l);
  unsigned hi = (unsigned)__builtin_amdgcn_readlane((int)(unsigned)(x >> 32), l);
  return ((ull)hi << 32) | (ull)lo;
}

__device__ __forceinline__ ull shflx32_64(ull x) {
  unsigned lo = (unsigned)__shfl_xor((int)(unsigned)(x & 0xffffffffull), 32);
  unsigned hi = (unsigned)__shfl_xor((int)(unsigned)(x >> 32), 32);
  return ((ull)hi << 32) | (ull)lo;
}

// ---------------- 1. per-image histogram of 13-bit keys ----------------
__global__ __launch_bounds__(512) void k_hist(const float* __restrict__ obj,
                                              unsigned* __restrict__ hist) {
  __shared__ unsigned h[NBINS];
  const int img = blockIdx.x >> 4;   // 16 blocks per image
  const int chunk = blockIdx.x & 15;
  for (int i = threadIdx.x; i < NBINS; i += 512) h[i] = 0u;
  __syncthreads();
  const int nv = N_ELEM / 4 / 16;    // 15625 float4 per chunk
  const float4* src = (const float4*)obj + (size_t)img * (N_ELEM / 4) + (size_t)chunk * nv;
  for (int v = threadIdx.x; v < nv; v += 512) {
    float4 x = src[v];
    atomicAdd(&h[fkey(x.x) >> KEY_SHIFT], 1u);
    atomicAdd(&h[fkey(x.y) >> KEY_SHIFT], 1u);
    atomicAdd(&h[fkey(x.z) >> KEY_SHIFT], 1u);
    atomicAdd(&h[fkey(x.w) >> KEY_SHIFT], 1u);
  }
  __syncthreads();
  unsigned* gh = hist + (size_t)img * NBINS;
  for (int i = threadIdx.x; i < NBINS; i += 512) {
    unsigned c = h[i];
    if (c) atomicAdd(&gh[i], c);
  }
}

// ---------------- 2. find per-image key threshold (2000th element's bin) ----------------
__global__ __launch_bounds__(256) void k_thresh(const unsigned* __restrict__ hist,
                                                unsigned* __restrict__ keylo) {
  const int img = blockIdx.x;
  const unsigned* gh = hist + (size_t)img * NBINS;
  __shared__ unsigned part[256];
  const int t = threadIdx.x;
  unsigned s = 0;
  const int hi = NBINS - 32 * t;     // exclusive top of this thread's region
  for (int b = hi - 32; b < hi; ++b) s += gh[b];
  part[t] = s;
  __syncthreads();
  if (t == 0) {
    unsigned acc = 0, excl = 0;
    int tstar = 255;
    for (int q = 0; q < 256; ++q) {
      unsigned na = acc + part[q];
      if (na >= PRE_NMS) { tstar = q; excl = acc; break; }
      acc = na;
    }
    const int bh = NBINS - 32 * tstar;
    unsigned a2 = excl, kl = 0;
    for (int b = bh - 1; b >= bh - 32; --b) {
      a2 += gh[b];
      if (a2 >= PRE_NMS) { kl = ((unsigned)b) << KEY_SHIFT; break; }
    }
    keylo[img] = kl;
  }
}

// ---------------- 3. compact candidates >= threshold (LDS-staged) ----------------
#define NCHUNKS 50
#define LCAP    1024

__global__ __launch_bounds__(512) void k_compact(const float* __restrict__ obj,
                                                 const unsigned* __restrict__ keylo,
                                                 unsigned* __restrict__ cnt,
                                                 ull* __restrict__ cand) {
  __shared__ ull lbuf[LCAP];
  __shared__ unsigned lcnt, sbase, slen;
  const int img = blockIdx.x / NCHUNKS;
  const int chunk = blockIdx.x % NCHUNKS;
  if (threadIdx.x == 0) lcnt = 0u;
  __syncthreads();
  const unsigned kl = keylo[img];
  const int nv = N_ELEM / 4 / NCHUNKS;   // 5000 float4 per chunk
  const float4* src = (const float4*)obj + (size_t)img * (N_ELEM / 4) + (size_t)chunk * nv;
  const unsigned base_idx = (unsigned)chunk * (N_ELEM / NCHUNKS);
  for (int v = threadIdx.x; v < nv; v += 512) {
    float4 x = src[v];
    unsigned k0 = fkey(x.x), k1 = fkey(x.y), k2 = fkey(x.z), k3 = fkey(x.w);
    unsigned bi = base_idx + 4u * (unsigned)v;
    if (k0 >= kl) { unsigned p = atomicAdd(&lcnt, 1u); if (p < LCAP) lbuf[p] = ((ull)k0 << 32) | (unsigned)(~bi); }
    if (k1 >= kl) { unsigned p = atomicAdd(&lcnt, 1u); if (p < LCAP) lbuf[p] = ((ull)k1 << 32) | (unsigned)(~(bi + 1u)); }
    if (k2 >= kl) { unsigned p = atomicAdd(&lcnt, 1u); if (p < LCAP) lbuf[p] = ((ull)k2 << 32) | (unsigned)(~(bi + 2u)); }
    if (k3 >= kl) { unsigned p = atomicAdd(&lcnt, 1u); if (p < LCAP) lbuf[p] = ((ull)k3 << 32) | (unsigned)(~(bi + 3u)); }
  }
  __syncthreads();
  if (threadIdx.x == 0) {
    unsigned n = lcnt; if (n > LCAP) n = LCAP;
    slen = n;
    sbase = n ? atomicAdd(&cnt[img], n) : 0u;
  }
  __syncthreads();
  ull* cimg = cand + (size_t)img * CAP;
  const unsigned b0 = sbase, n0 = slen;
  for (unsigned i = threadIdx.x; i < n0; i += 512) {
    unsigned p = b0 + i;
    if (p < CAP) cimg[p] = lbuf[i];
  }
}

// ---------------- 4. per-image bitonic sort + decode/clip/width-mask ----------------
__global__ __launch_bounds__(1024) void k_sortdecode(const ull* __restrict__ cand,
                                                     const unsigned* __restrict__ cnt,
                                                     const float2* __restrict__ delta,
                                                     const float2* __restrict__ anchor,
                                                     float2* __restrict__ boxes,
                                                     ull* __restrict__ validm) {
  __shared__ ull sk[SORT_N];
  const int img = blockIdx.x;
  unsigned M = cnt[img]; if (M > CAP) M = CAP;
  const ull* cimg = cand + (size_t)img * CAP;
  for (int i = threadIdx.x; i < SORT_N; i += 1024) sk[i] = (i < (int)M) ? cimg[i] : 0ull;
  __syncthreads();
  for (int k = 2; k <= SORT_N; k <<= 1) {
    for (int j = k >> 1; j > 0; j >>= 1) {
      for (int p = threadIdx.x; p < SORT_N / 2; p += 1024) {
        int i = ((p & ~(j - 1)) << 1) | (p & (j - 1));
        int ixj = i | j;
        ull a = sk[i], b = sk[ixj];
        bool asc = (i & k) != 0;
        bool sw = asc ? (a > b) : (a < b);   // overall descending
        if (sw) { sk[i] = b; sk[ixj] = a; }
      }
      __syncthreads();
    }
  }
  // decode top PRE_NMS, write padded boxes + validity ballot
  for (int i = threadIdx.x; i < KPAD; i += 1024) {
    float bx0 = 0.f, bx1 = 0.f;
    bool valid = false;
    if (i < PRE_NMS) {
      ull e = sk[i];
      unsigned idx = ~((unsigned)e);
      float2 d = delta[(size_t)img * N_ELEM + idx];
      float2 a = anchor[(size_t)img * N_ELEM + idx];
      float aw = a.y - a.x;
      float ac = a.x + 0.5f * aw;
      float dx = d.x;
      float dw = fminf(d.y, 4.135f);
      float pc = dx * aw + ac;
      float pw = expf(dw) * aw;
      float x0 = pc - 0.5f * pw;
      float x1 = pc + 0.5f * pw;
      x0 = fminf(fmaxf(x0, 0.f), 360.f);
      x1 = fminf(fmaxf(x1, 0.f), 360.f);
      bx0 = x0; bx1 = x1;
      valid = (x1 - x0) >= 10.0f;
    }
    boxes[(size_t)img * KPAD + i] = make_float2(bx0, bx1);
    ull bm = __ballot(valid);
    if ((threadIdx.x & 63) == 0) validm[img * 32 + (i >> 6)] = bm;
  }
}

// ---------------- 5. suppression bit-matrix, wave-per-64x64-tile ----------------
__global__ __launch_bounds__(256) void k_matrix(const float2* __restrict__ boxes,
                                                ull* __restrict__ mat,
                                                ull* __restrict__ dspan) {
  const int wid = blockIdx.x * 4 + (threadIdx.x >> 6);   // global wave/tile id
  const int lane = threadIdx.x & 63;
  const int img = wid >> 10;          // 32*32 tiles per image
  const int RI = (wid >> 5) & 31;
  const int CJ = wid & 31;
  ull* mimg = mat + (size_t)img * KPAD * 32;
  ull myword = 0ull;
  if (CJ >= RI) {
    const float2* bimg = boxes + (size_t)img * KPAD;
    float2 rb = bimg[RI * 64 + lane];   // row boxes (this lane holds row `lane`)
    float2 cb = bimg[CJ * 64 + lane];   // col box for this lane
    float acol = cb.y - cb.x;
    const bool diag = (RI == CJ);
#pragma unroll 8
    for (int i = 0; i < 64; ++i) {
      float b0x = __uint_as_float((unsigned)__builtin_amdgcn_readlane((int)__float_as_uint(rb.x), i));
      float b0y = __uint_as_float((unsigned)__builtin_amdgcn_readlane((int)__float_as_uint(rb.y), i));
      float a0 = b0y - b0x;
      float lo = fmaxf(b0x, cb.x);
      float hi = fminf(b0y, cb.y);
      float inter = fmaxf(hi - lo, 0.f);
      float den = fmaxf((a0 + acol) - inter, 1e-8f);
      bool sup = (inter / den) > 0.7f;
      if (diag) sup = sup && (lane > i);
      ull bm = __ballot(sup);
      if (lane == i) myword = bm;
    }
    if (diag) dspan[(size_t)img * KPAD + RI * 64 + lane] = myword;
  }
  mimg[(size_t)(RI * 64 + lane) * 32 + CJ] = myword;
}

// ---------------- 6. tile greedy scan, inline-asm pipelined loads ----------------
// Lane (h=lane>>5, w=lane&31) owns word w, rows j=h*32..h*32+31 of each tile.
// All VMEM in the loop is asm volatile (cannot be reordered/collapsed):
//   tile t body: [issue t+1: 1 dsp + 32 mat dwordx2 loads] -> s_waitcnt vmcnt(33)
//   -> sched_barrier -> SALU scan of t's diag -> VALU apply t -> half-combine.
#define LDOFF(dst, a, OFS) \
  asm volatile("global_load_dwordx2 %0, %1, off offset:" OFS : "=v"(dst) : "v"(a));

#define LD32(VN, a0, a1) \
  LDOFF(VN[0],a0,"0")    LDOFF(VN[1],a0,"256")  LDOFF(VN[2],a0,"512")  LDOFF(VN[3],a0,"768")  \
  LDOFF(VN[4],a0,"1024") LDOFF(VN[5],a0,"1280") LDOFF(VN[6],a0,"1536") LDOFF(VN[7],a0,"1792") \
  LDOFF(VN[8],a0,"2048") LDOFF(VN[9],a0,"2304") LDOFF(VN[10],a0,"2560") LDOFF(VN[11],a0,"2816") \
  LDOFF(VN[12],a0,"3072") LDOFF(VN[13],a0,"3328") LDOFF(VN[14],a0,"3584") LDOFF(VN[15],a0,"3840") \
  LDOFF(VN[16],a1,"0")    LDOFF(VN[17],a1,"256")  LDOFF(VN[18],a1,"512")  LDOFF(VN[19],a1,"768") \
  LDOFF(VN[20],a1,"1024") LDOFF(VN[21],a1,"1280") LDOFF(VN[22],a1,"1536") LDOFF(VN[23],a1,"1792") \
  LDOFF(VN[24],a1,"2048") LDOFF(VN[25],a1,"2304") LDOFF(VN[26],a1,"2560") LDOFF(VN[27],a1,"2816") \
  LDOFF(VN[28],a1,"3072") LDOFF(VN[29],a1,"3328") LDOFF(VN[30],a1,"3584") LDOFF(VN[31],a1,"3840")

#define WAITV(NSTR) do { \
    asm volatile("s_waitcnt vmcnt(" NSTR ")" ::: "memory"); \
    __builtin_amdgcn_sched_barrier(0); \
  } while (0)

__global__ __launch_bounds__(64, 1) void k_scan(const ull* __restrict__ mat,
                                                const ull* __restrict__ dspan,
                                                const ull* __restrict__ validm,
                                                const float2* __restrict__ boxes,
                                                float2* __restrict__ out) {
  const int img = blockIdx.x;
  const int lane = threadIdx.x;
  const int w = lane & 31;
  const int h = lane >> 5;
  ull rm = ~validm[img * 32 + w];   // lanes 32..63 mirror lanes 0..31
  asm volatile("" :: "v"(rm));      // materialize before asm loads enter the queue

  const ull mbase = (ull)(uintptr_t)(mat + (size_t)img * KPAD * 32);
  const ull dbase = (ull)(uintptr_t)(dspan + (size_t)img * KPAD);

  ull va[32], vb[32], dspA, dspB;

  // prologue: issue tile 0 (predicate w>=0 is all lanes)
  {
    ull da = dbase + (ull)lane * 8ull;
    LDOFF(dspA, da, "0")
    ull a0 = mbase + (ull)(h * 32) * 256ull + (ull)w * 8ull;
    ull a1 = a0 + 4096ull;
    LD32(va, a0, a1)
  }

#define TILEBODY(VC, DC, VN, DN, T, DO_ISSUE) do {                         \
    if (DO_ISSUE) {                                                        \
      ull da_ = dbase + (ull)(64 * ((T) + 1) + lane) * 8ull;               \
      LDOFF(DN, da_, "0")                                                  \
      if (w >= (T) + 1) {                                                  \
        ull a0_ = mbase + ((ull)(((T) + 1) * 64 + h * 32)) * 256ull + (ull)w * 8ull; \
        ull a1_ = a0_ + 4096ull;                                           \
        LD32(VN, a0_, a1_)                                                 \
      }                                                                    \
      WAITV("33");                                                         \
    } else {                                                               \
      WAITV("0");                                                          \
    }                                                                      \
    ull alive_ = ~readlane64(rm, (T));                                     \
    _Pragma("unroll")                                                      \
    for (int j = 0; j < 64; ++j) {                                         \
      ull dj_ = readlane64(DC, j);                                         \
      ull mj_ = 0ull - ((alive_ >> j) & 1ull);                             \
      alive_ &= ~(dj_ & mj_);                                              \
    }                                                                      \
    if (w >= (T)) {                                                        \
      unsigned ah_ = (unsigned)(h ? (alive_ >> 32) : alive_);              \
      _Pragma("unroll")                                                    \
      for (int j = 0; j < 32; ++j) {                                       \
        ull mj_ = 0ull - (ull)((ah_ >> j) & 1u);                           \
        rm |= mj_ & VC[j];                                                 \
      }                                                                    \
    }                                                                      \
    rm |= shflx32_64(rm);                                                  \
  } while (0)

  for (int tt = 0; tt < 32; tt += 2) {
    TILEBODY(va, dspA, vb, dspB, tt, true);
    TILEBODY(vb, dspB, va, dspA, tt + 1, (tt + 1) < 31);
  }
#undef TILEBODY

  // keep mask = ~rm (rows >= 2000 were marked invalid -> removed)
  ull keep = ~rm;
  int cw = (lane < 32) ? __popcll(keep) : 0;
  int v = cw;
#pragma unroll
  for (int off = 1; off < 64; off <<= 1) {
    int n = __shfl_up(v, off);
    if (lane >= off) v += n;
  }
  int excl = v - cw;
  int total = __shfl(v, 63);
  if (lane < 32) {
    int r = excl;
    ull kk = keep;
    while (kk) {
      int t = __ffsll(kk) - 1;
      kk &= kk - 1;
      if (r < POST_NMS) {
        out[(size_t)img * POST_NMS + r] = boxes[(size_t)img * KPAD + (w * 64 + t)];
      }
      ++r;
    }
  }
  for (int r = total + lane; r < POST_NMS; r += 64) {
    out[(size_t)img * POST_NMS + r] = make_float2(0.f, 0.f);
  }
}

extern "C" void kernel_launch(void* const* d_in, const int* in_sizes, int n_in,
                              void* d_out, int out_size, void* d_ws, size_t ws_size,
                              hipStream_t stream) {
  const float* obj = (const float*)d_in[0];
  const float2* delta = (const float2*)d_in[1];
  const float2* anchor = (const float2*)d_in[2];
  float2* out = (float2*)d_out;
  char* ws = (char*)d_ws;

  unsigned* hist = (unsigned*)(ws + OFF_HIST);
  unsigned* cnt = (unsigned*)(ws + OFF_CNT);
  unsigned* keylo = (unsigned*)(ws + OFF_KEYLO);
  ull* cand = (ull*)(ws + OFF_CAND);
  float2* boxes = (float2*)(ws + OFF_BOXES);
  ull* validm = (ull*)(ws + OFF_VALID);
  ull* dspan = (ull*)(ws + OFF_DSPAN);
  ull* mat = (ull*)(ws + OFF_MAT);

  // zero hist + cnt (keylo overwritten)
  hipMemsetAsync(ws, 0, OFF_KEYLO + 4096, stream);

  k_hist<<<256, 512, 0, stream>>>(obj, hist);
  k_thresh<<<16, 256, 0, stream>>>(hist, keylo);
  k_compact<<<16 * NCHUNKS, 512, 0, stream>>>(obj, keylo, cnt, cand);
  k_sortdecode<<<16, 1024, 0, stream>>>(cand, cnt, delta, anchor, boxes, validm);
  k_matrix<<<4096, 256, 0, stream>>>(boxes, mat, dspan);
  k_scan<<<16, 64, 0, stream>>>(mat, dspan, validm, boxes, out);
}